// Round 8
// baseline (176.391 us; speedup 1.0000x reference)
//
#include <hip/hip_runtime.h>
#include <cstdint>

#define NVv 40000
#define NCc 300
#define NIi 7000
#define NNn 47300
#define DD 128
#define E1N 500000
#define E2N 500000

#define SCAN_N (3 * NVv)                     // sections: g1hi | g1lo | g2
#define SCAN_NB ((SCAN_N + 1023) / 1024)
#define MLPB ((NNn + 63) / 64)               // 740 MLP blocks
#define EBLK ((E1N + E2N + 255) / 256)       // 3907 hist blocks
#define WBLK 32                              // weight-convert blocks (32768 elems)

typedef __attribute__((ext_vector_type(8))) short short8v;
typedef __attribute__((ext_vector_type(4))) short short4v;
typedef __attribute__((ext_vector_type(4))) float f32x4;

__device__ __forceinline__ short f2bf(float f) {   // RNE f32->bf16
    unsigned u = __float_as_uint(f);
    u += 0x7FFF + ((u >> 16) & 1);
    return (short)(u >> 16);
}
__device__ __forceinline__ float bf2f(short s) {
    return __uint_as_float(((unsigned)(unsigned short)s) << 16);
}

// Row of the virtual concatenated [visit; ccs; icd] array.
__device__ __forceinline__ const float* node_row(const float* __restrict__ v,
                                                 const float* __restrict__ c,
                                                 const float* __restrict__ i, int t) {
    return t < NVv ? v + (size_t)t * DD
         : t < NVv + NCc ? c + (size_t)(t - NVv) * DD
                         : i + (size_t)(t - NVv - NCc) * DD;
}

// Edge histogram (3 sections) + bf16 weight pre-conversion in trailing blocks.
// No LDS here -> full occupancy for the atomic-heavy part.
__global__ void hist_prep(const int* __restrict__ g1, const int* __restrict__ g2,
                          int* __restrict__ cnt,
                          const float* __restrict__ w1, const float* __restrict__ w2,
                          short* __restrict__ Wbf) {
    int bid = blockIdx.x;
    if (bid >= EBLK) {                       // ---- weight convert: 2x128x128 ----
        int e = (bid - EBLK) * 1024 + threadIdx.x * 4;
        float4 v = e < DD * DD ? *(const float4*)(w1 + e)
                               : *(const float4*)(w2 + e - DD * DD);
        short4v s;
        s.x = f2bf(v.x); s.y = f2bf(v.y); s.z = f2bf(v.z); s.w = f2bf(v.w);
        *(short4v*)(Wbf + e) = s;
        return;
    }
    int gid = bid * 256 + threadIdx.x;
    if (gid < E1N) {
        int h = g1[gid];
        if (h < NVv) {
            int t = g1[E1N + gid];
            atomicAdd(cnt + (t >= NVv ? h : NVv + h), 1);
        }
    } else if (gid < E1N + E2N) {
        int h = g2[gid - E1N];
        if (h < NVv) atomicAdd(cnt + 2 * NVv + h, 1);
    }
}

// Per-node MLP via bf16 MFMA (weights pre-converted), then build gather tables:
//   TC[n]: 32 chunks x 16B, chunk q = bf16 {el[4q..4q+3], c[4q..4q+3]}  (512 B)
//   O [n]: 128 bf16 offsets                                             (256 B)
__global__ __launch_bounds__(256) void node_mlp(
        const float* __restrict__ vc, const float* __restrict__ cc,
        const float* __restrict__ ic,
        const float* __restrict__ vo, const float* __restrict__ co,
        const float* __restrict__ io,
        const short* __restrict__ Wbf,
        const float* __restrict__ b1, const float* __restrict__ b2,
        short* __restrict__ TC, short* __restrict__ O) {
    __shared__ short wbuf[128][136];
    __shared__ short hbuf[64][136];
    const int tid = threadIdx.x;
    const int lane = tid & 63, wv = tid >> 6;
    const int n0b = blockIdx.x * 64;
    const int n0 = n0b + wv * 16;
    const int colw = lane & 15;              // col within a 16-tile
    const int k0 = (lane >> 4) * 8;          // k sub-offset for A/B frags

    // stage w1 (bf16, pre-converted): 2048 16B-chunks, ds_write_b128
    const short8v* wsrc = (const short8v*)Wbf;
    #pragma unroll
    for (int i = 0; i < 8; ++i) {
        int cid = i * 256 + tid;             // 16 chunks per 128-col row
        *(short8v*)&wbuf[cid >> 4][(cid & 15) * 8] = wsrc[cid];
    }

    // A frags (layer 1) straight from global: row = n0 + (lane&15)
    int arow = n0 + colw; if (arow >= NNn) arow = NNn - 1;
    const float* ar = node_row(vc, cc, ic, arow);
    short8v a[4];
    #pragma unroll
    for (int kf = 0; kf < 4; ++kf) {
        const float* p = ar + kf * 32 + k0;
        float4 x = *(const float4*)p;
        float4 y = *(const float4*)(p + 4);
        short8v t;
        t[0] = f2bf(x.x); t[1] = f2bf(x.y); t[2] = f2bf(x.z); t[3] = f2bf(x.w);
        t[4] = f2bf(y.x); t[5] = f2bf(y.y); t[6] = f2bf(y.z); t[7] = f2bf(y.w);
        a[kf] = t;
    }
    __syncthreads();

    // layer 1: h = relu(A @ W1^T + b1) -> hbuf
    #pragma unroll
    for (int jt = 0; jt < 8; ++jt) {
        int j = jt * 16 + colw;
        float bb = b1[j];
        f32x4 acc = {bb, bb, bb, bb};
        #pragma unroll
        for (int kf = 0; kf < 4; ++kf) {
            short8v b = *(short8v*)&wbuf[j][kf * 32 + k0];
            acc = __builtin_amdgcn_mfma_f32_16x16x32_bf16(a[kf], b, acc, 0, 0, 0);
        }
        #pragma unroll
        for (int r = 0; r < 4; ++r)
            hbuf[wv * 16 + (lane >> 4) * 4 + r][j] = f2bf(fmaxf(acc[r], 0.f));
    }
    __syncthreads();                         // all waves done reading wbuf(w1)

    // A frags (layer 2) from own hbuf rows
    short8v a2[4];
    #pragma unroll
    for (int kf = 0; kf < 4; ++kf)
        a2[kf] = *(short8v*)&hbuf[wv * 16 + colw][kf * 32 + k0];

    // stage w2 over wbuf
    const short8v* wsrc2 = (const short8v*)(Wbf + DD * DD);
    #pragma unroll
    for (int i = 0; i < 8; ++i) {
        int cid = i * 256 + tid;
        *(short8v*)&wbuf[cid >> 4][(cid & 15) * 8] = wsrc2[cid];
    }
    __syncthreads();

    // layer 2 + exp -> hbuf as bf16 (hbuf A-frags already consumed)
    #pragma unroll
    for (int jt = 0; jt < 8; ++jt) {
        int j = jt * 16 + colw;
        float bb = b2[j];
        f32x4 acc = {bb, bb, bb, bb};
        #pragma unroll
        for (int kf = 0; kf < 4; ++kf) {
            short8v b = *(short8v*)&wbuf[j][kf * 32 + k0];
            acc = __builtin_amdgcn_mfma_f32_16x16x32_bf16(a2[kf], b, acc, 0, 0, 0);
        }
        #pragma unroll
        for (int r = 0; r < 4; ++r)
            hbuf[wv * 16 + (lane >> 4) * 4 + r][j] = f2bf(__expf(acc[r]));
    }
    __syncthreads();

    // TC build: 64 rows x 32 chunks = 2048 chunks / 256 threads = 8 iters
    #pragma unroll
    for (int i = 0; i < 8; ++i) {
        int cid = i * 256 + tid;
        int r = cid >> 5, p = cid & 31;
        int n = n0b + r;
        if (n >= NNn) continue;
        const float* cr = node_row(vc, cc, ic, n);
        float4 cv = *(const float4*)(cr + 4 * p);
        short4v el = *(const short4v*)&hbuf[r][4 * p];
        short8v s;
        s[0] = el.x; s[1] = el.y; s[2] = el.z; s[3] = el.w;
        s[4] = f2bf(cv.x); s[5] = f2bf(cv.y); s[6] = f2bf(cv.z); s[7] = f2bf(cv.w);
        *(short8v*)(TC + (size_t)n * 256 + 8 * p) = s;
    }
    // O build: 64 rows x 32 chunks of 8B
    #pragma unroll
    for (int i = 0; i < 8; ++i) {
        int cid = i * 256 + tid;
        int r = cid >> 5, l = cid & 31;
        int n = n0b + r;
        if (n >= NNn) continue;
        const float* orow = node_row(vo, co, io, n);
        float4 v = *(const float4*)(orow + 4 * l);
        short4v s;
        s.x = f2bf(v.x); s.y = f2bf(v.y); s.z = f2bf(v.z); s.w = f2bf(v.w);
        *(short4v*)(O + (size_t)n * 128 + 4 * l) = s;
    }
}

__global__ __launch_bounds__(1024) void scan_partial(const int* __restrict__ cnt,
                                                     int* __restrict__ bsum) {
    __shared__ int ws[16];
    int tid = threadIdx.x, lane = tid & 63, wvi = tid >> 6;
    int i = blockIdx.x * 1024 + tid;
    int v = (i < SCAN_N) ? cnt[i] : 0;
    #pragma unroll
    for (int off = 32; off; off >>= 1) v += __shfl_xor(v, off);
    if (lane == 0) ws[wvi] = v;
    __syncthreads();
    if (tid == 0) {
        int s = 0;
        #pragma unroll
        for (int w = 0; w < 16; ++w) s += ws[w];
        bsum[blockIdx.x] = s;
    }
}

// Final scan; block offset = reduce(bsum[0..blockIdx)) computed in-kernel.
__global__ __launch_bounds__(1024) void scan_final(const int* __restrict__ cnt,
                                                   const int* __restrict__ bsum,
                                                   int* __restrict__ base,
                                                   int* __restrict__ cur) {
    __shared__ int ws[16];
    __shared__ int s_off;
    int tid = threadIdx.x, lane = tid & 63, wvi = tid >> 6;

    int pre = 0;
    for (int j = tid; j < (int)blockIdx.x; j += 1024) pre += bsum[j];
    #pragma unroll
    for (int off = 32; off; off >>= 1) pre += __shfl_xor(pre, off);
    if (lane == 0) ws[wvi] = pre;
    __syncthreads();
    if (tid == 0) {
        int s = 0;
        #pragma unroll
        for (int w = 0; w < 16; ++w) s += ws[w];
        s_off = s;
    }
    __syncthreads();
    int boff = s_off;
    __syncthreads();                         // ws reuse below

    int i = blockIdx.x * 1024 + tid;
    int v = (i < SCAN_N) ? cnt[i] : 0;
    int incl = v;
    #pragma unroll
    for (int off = 1; off < 64; off <<= 1) {
        int o = __shfl_up(incl, off);
        if (lane >= off) incl += o;
    }
    if (lane == 63) ws[wvi] = incl;
    __syncthreads();
    int wpre = 0;
    for (int w = 0; w < wvi; ++w) wpre += ws[w];
    int excl = boff + wpre + incl - v;
    if (i < SCAN_N) { base[i] = excl; cur[i] = excl; }
    if (i == SCAN_N - 1) base[SCAN_N] = excl + v;   // grand total
}

__global__ void scatter(const int* __restrict__ g1, const int* __restrict__ g2,
                        int* __restrict__ cur, unsigned short* __restrict__ csr) {
    int gid = blockIdx.x * blockDim.x + threadIdx.x;
    if (gid < E1N) {
        int h = g1[gid];
        if (h < NVv) {
            int t = g1[E1N + gid];
            int sec = t >= NVv ? h : NVv + h;
            csr[atomicAdd(cur + sec, 1)] = (unsigned short)t;
        }
    } else if (gid < E1N + E2N) {
        int e = gid - E1N;
        int h = g2[e];
        if (h < NVv)
            csr[atomicAdd(cur + 2 * NVv + h, 1)] = (unsigned short)g2[E2N + e];
    }
}

__device__ __forceinline__ void acc8(short8v a, float d[4], float n[4]) {
    #pragma unroll
    for (int j = 0; j < 4; ++j) {
        float w = bf2f(a[j]);
        d[j] += w;
        n[j] = fmaf(w, bf2f(a[4 + j]), n[j]);
    }
}
__device__ __forceinline__ void acc4(short4v o, float m[4]) {
    m[0] = fmaxf(m[0], bf2f(o.x));
    m[1] = fmaxf(m[1], bf2f(o.y));
    m[2] = fmaxf(m[2], bf2f(o.z));
    m[3] = fmaxf(m[3], bf2f(o.w));
}

// One wave per segment, 2 edges per gather instruction: lanes 0-31 process
// even edges, lanes 32-63 odd edges (16B TC / 8B O per lane covers a full
// row across 32 lanes). Odd tails read the memset-zero dummy row NNn.
// Halves combined via shfl_xor(32) at the end.
__global__ void seg_fused(const int* __restrict__ base,
                          const unsigned short* __restrict__ csr,
                          const short* __restrict__ TC, const short* __restrict__ O,
                          float* __restrict__ out0, float* __restrict__ out1) {
    int seg = __builtin_amdgcn_readfirstlane(
        blockIdx.x * (blockDim.x >> 6) + (threadIdx.x >> 6));
    if (seg >= NVv) return;
    int lane = threadIdx.x & 63;
    int half = lane >> 5, q = lane & 31;
    float d[4] = {0.f, 0.f, 0.f, 0.f};
    float n[4] = {0.f, 0.f, 0.f, 0.f};
    float m[4] = {0.f, 0.f, 0.f, 0.f};       // 0 == relu floor + empty default

    // ---- g1 & t>=NV: softmax + offset max ----
    int s = base[seg], e = base[seg + 1];
    for (int c = s; c < e; c += 64) {
        int lim = e - c; if (lim > 64) lim = 64;
        int tl = (lane < lim) ? (int)csr[c + lane] : NNn;
        int k = 0;
        for (; k + 8 <= lim; k += 8) {
            short8v a[4]; short4v o[4];
            #pragma unroll
            for (int u = 0; u < 4; ++u) {
                int t = __shfl(tl, k + 2 * u + half);
                a[u] = *(const short8v*)(TC + ((size_t)t << 8) + 8 * q);
                o[u] = *(const short4v*)(O + ((size_t)t << 7) + 4 * q);
            }
            #pragma unroll
            for (int u = 0; u < 4; ++u) { acc8(a[u], d, n); acc4(o[u], m); }
        }
        for (; k < lim; k += 2) {
            int t = __shfl(tl, k + half);
            short8v a = *(const short8v*)(TC + ((size_t)t << 8) + 8 * q);
            short4v o = *(const short4v*)(O + ((size_t)t << 7) + 4 * q);
            acc8(a, d, n); acc4(o, m);
        }
    }

    // ---- g1 & t<NV: softmax only ----
    s = base[NVv + seg]; e = base[NVv + seg + 1];
    for (int c = s; c < e; c += 64) {
        int lim = e - c; if (lim > 64) lim = 64;
        int tl = (lane < lim) ? (int)csr[c + lane] : NNn;
        int k = 0;
        for (; k + 8 <= lim; k += 8) {
            short8v a[4];
            #pragma unroll
            for (int u = 0; u < 4; ++u) {
                int t = __shfl(tl, k + 2 * u + half);
                a[u] = *(const short8v*)(TC + ((size_t)t << 8) + 8 * q);
            }
            #pragma unroll
            for (int u = 0; u < 4; ++u) acc8(a[u], d, n);
        }
        for (; k < lim; k += 2) {
            int t = __shfl(tl, k + half);
            short8v a = *(const short8v*)(TC + ((size_t)t << 8) + 8 * q);
            acc8(a, d, n);
        }
    }

    // ---- g2: offset max only ----
    s = base[2 * NVv + seg]; e = base[2 * NVv + seg + 1];
    for (int c = s; c < e; c += 64) {
        int lim = e - c; if (lim > 64) lim = 64;
        int tl = (lane < lim) ? (int)csr[c + lane] : NNn;
        int k = 0;
        for (; k + 8 <= lim; k += 8) {
            short4v o[4];
            #pragma unroll
            for (int u = 0; u < 4; ++u) {
                int t = __shfl(tl, k + 2 * u + half);
                o[u] = *(const short4v*)(O + ((size_t)t << 7) + 4 * q);
            }
            #pragma unroll
            for (int u = 0; u < 4; ++u) acc4(o[u], m);
        }
        for (; k < lim; k += 2) {
            int t = __shfl(tl, k + half);
            short4v o = *(const short4v*)(O + ((size_t)t << 7) + 4 * q);
            acc4(o, m);
        }
    }

    // combine the two 32-lane halves
    #pragma unroll
    for (int j = 0; j < 4; ++j) {
        d[j] += __shfl_xor(d[j], 32);
        n[j] += __shfl_xor(n[j], 32);
        m[j] = fmaxf(m[j], __shfl_xor(m[j], 32));
    }
    float v[4], ss = 0.f;
    #pragma unroll
    for (int j = 0; j < 4; ++j) {
        v[j] = d[j] > 0.f ? n[j] / d[j] : 0.f;
        ss += v[j] * v[j];
    }
    #pragma unroll
    for (int off = 16; off; off >>= 1) ss += __shfl_xor(ss, off);
    float inv = 1.f / fmaxf(sqrtf(ss), 1e-12f);
    size_t b = (size_t)seg * DD + 4 * q;
    if (half == 0)
        *(float4*)(out0 + b) = make_float4(v[0]*inv, v[1]*inv, v[2]*inv, v[3]*inv);
    else
        *(float4*)(out1 + b) = make_float4(m[0], m[1], m[2], m[3]);
}

extern "C" void kernel_launch(void* const* d_in, const int* in_sizes, int n_in,
                              void* d_out, int out_size, void* d_ws, size_t ws_size,
                              hipStream_t stream) {
    const float* vc  = (const float*)d_in[0];
    const float* vo  = (const float*)d_in[1];
    const float* cc  = (const float*)d_in[2];
    const float* co  = (const float*)d_in[3];
    const float* ic  = (const float*)d_in[4];
    const float* io  = (const float*)d_in[5];
    // d_in[6] visit_time, d_in[11..14] time-net params: dead (lam == 1.0)
    const float* aw1 = (const float*)d_in[7];
    const float* ab1 = (const float*)d_in[8];
    const float* aw2 = (const float*)d_in[9];
    const float* ab2 = (const float*)d_in[10];
    const int*   g1  = (const int*)d_in[15];
    const int*   g2  = (const int*)d_in[16];

    float* out0 = (float*)d_out;                    // [NV,128] final emb
    float* out1 = out0 + (size_t)NVv * DD;          // [NV,128] final offset

    short* TC  = (short*)d_ws;                      // [NN+1,256] bf16 tables
    short* O   = TC + (size_t)(NNn + 1) * 256;      // [NN+1,128] bf16 offsets
    int* cnt   = (int*)(O + (size_t)(NNn + 1) * 128);  // SCAN_N (16B-aligned)
    int* base  = cnt + SCAN_N;                      // SCAN_N + 4 (keep 16B align)
    int* cur   = base + SCAN_N + 4;                 // SCAN_N
    int* bsum  = cur + SCAN_N;                      // 128
    short* Wbf = (short*)(bsum + 128);              // 2*128*128 bf16 weights
    unsigned short* csr = (unsigned short*)(Wbf + 2 * DD * DD);  // <= E1N+E2N

    hipMemsetAsync(cnt, 0, SCAN_N * sizeof(int), stream);
    hipMemsetAsync(TC + (size_t)NNn * 256, 0, 512, stream);   // dummy row (sum-neutral)
    hipMemsetAsync(O + (size_t)NNn * 128, 0, 256, stream);    // dummy row (max-neutral)

    hist_prep<<<EBLK + WBLK, 256, 0, stream>>>(g1, g2, cnt, aw1, aw2, Wbf);
    scan_partial<<<SCAN_NB, 1024, 0, stream>>>(cnt, bsum);
    scan_final<<<SCAN_NB, 1024, 0, stream>>>(cnt, bsum, base, cur);
    scatter<<<(E1N + E2N + 255) / 256, 256, 0, stream>>>(g1, g2, cur, csr);

    node_mlp<<<MLPB, 256, 0, stream>>>(vc, cc, ic, vo, co, io,
                                       Wbf, ab1, ab2, TC, O);

    seg_fused<<<(NVv + 3) / 4, 256, 0, stream>>>(base, csr, TC, O, out0, out1);
}